// Round 7
// baseline (280.779 us; speedup 1.0000x reference)
//
#include <hip/hip_runtime.h>
#include <hip/hip_bf16.h>
#include <math.h>

// Problem constants
#define LL 4096
#define DD 1024
#define NN 16
#define KK 4
#define BB 2
#define MM (BB * LL)   // 8192
#define NC 64          // scan chunks
#define LC 64          // chunk length (NC*LC == LL)

typedef unsigned short ushort_t;
typedef short s16x8 __attribute__((ext_vector_type(8)));
typedef float f32x4 __attribute__((ext_vector_type(4)));
typedef unsigned int u32;

__device__ __forceinline__ ushort_t f2bf(float f) {
  __hip_bfloat16 h = __float2bfloat16(f);
  return *reinterpret_cast<ushort_t*>(&h);
}
__device__ __forceinline__ float bf2f(ushort_t u) {
  union { u32 i; float f; } c;
  c.i = ((u32)u) << 16;
  return c.f;
}

// ---------------------------------------------------------------------------
// bf16 MFMA GEMM, B-transposed: C[M,N] = A[M,K] @ BT[N,K]^T + bias, K=1024.
// 128x128 tile, BK=32, 256 threads (4 waves, 2x2), 16x16x32 MFMA,
// global_load_lds width-16 staging (m97 structure).
// R7: (a) XOR k-chunk swizzle — LDS rows store chunk c at slot c^((row>>1)&3)
//     (permuted in the DMA *source* address, so lane->LDS stays contiguous);
//     fragment reads then cover all 32 banks at 2-way (free) instead of the
//     8-way conflict of the naive layout (was 4.19M conflict cycles).
//     (b) 1D grid with col-groups of 8 so the active B strip (2 MB) stays
//     L2-resident instead of re-streaming 4.2 MB per row tile.
// ---------------------------------------------------------------------------
template <bool BF16OUT>
__global__ __launch_bounds__(256) void gemm_bt_mfma(
    const ushort_t* __restrict__ A,   // [M,K] bf16
    const ushort_t* __restrict__ BT,  // [N,K] bf16
    const float* __restrict__ bias,
    void* __restrict__ Cv, int N) {
  constexpr int K = 1024;
  __shared__ ushort_t As[128 * 32];
  __shared__ ushort_t Bs[128 * 32];

  const int tid = threadIdx.x;
  const int lane = tid & 63;
  const int w = tid >> 6;            // wave 0..3
  const int wm = w & 1, wn = w >> 1; // 2x2 wave grid over the 128x128 tile

  // 1D block swizzle: col-groups of 8 over 64 row tiles
  const int GY = MM / 128;  // 64
  const int bid = blockIdx.x;
  const int group = bid / (8 * GY);
  const int rem = bid % (8 * GY);
  const int row0 = (rem / 8) * 128;
  const int col0 = (group * 8 + (rem & 7)) * 128;

  const int lrow = lane >> 2;               // 0..15: row within 16-row group
  const int lkc = (lane & 3) ^ ((lrow >> 1) & 3);  // swizzled source k-chunk

  f32x4 acc[4][4];
#pragma unroll
  for (int i = 0; i < 4; ++i)
#pragma unroll
    for (int j = 0; j < 4; ++j) acc[i][j] = (f32x4){0.f, 0.f, 0.f, 0.f};

  const int frow = lane & 15;
  const int quad = lane >> 4;
  const int sw = (frow >> 1) & 3;  // read-side swizzle key

  for (int k0 = 0; k0 < K; k0 += 32) {
#pragma unroll
    for (int it = 0; it < 2; ++it) {
      int r = it * 64 + w * 16;  // wave-uniform 16-row group
      __builtin_amdgcn_global_load_lds(
          (const __attribute__((address_space(1))) u32*)(A + (size_t)(row0 + r + lrow) * K + k0 + lkc * 8),
          (__attribute__((address_space(3))) u32*)(As + r * 32), 16, 0, 0);
      __builtin_amdgcn_global_load_lds(
          (const __attribute__((address_space(1))) u32*)(BT + (size_t)(col0 + r + lrow) * K + k0 + lkc * 8),
          (__attribute__((address_space(3))) u32*)(Bs + r * 32), 16, 0, 0);
    }
    __syncthreads();

    s16x8 af[4], bf[4];
#pragma unroll
    for (int mi = 0; mi < 4; ++mi)
      af[mi] = *(const s16x8*)&As[(wm * 64 + mi * 16 + frow) * 32 + (quad ^ sw) * 8];
#pragma unroll
    for (int ni = 0; ni < 4; ++ni)
      bf[ni] = *(const s16x8*)&Bs[(wn * 64 + ni * 16 + frow) * 32 + (quad ^ sw) * 8];
#pragma unroll
    for (int mi = 0; mi < 4; ++mi)
#pragma unroll
      for (int ni = 0; ni < 4; ++ni)
        acc[mi][ni] = __builtin_amdgcn_mfma_f32_16x16x32_bf16(
            af[mi], bf[ni], acc[mi][ni], 0, 0, 0);
    __syncthreads();
  }

  // Epilogue: C/D layout col=lane&15, row=quad*4+reg
#pragma unroll
  for (int mi = 0; mi < 4; ++mi) {
#pragma unroll
    for (int ni = 0; ni < 4; ++ni) {
      int col = col0 + wn * 64 + ni * 16 + frow;
      float b = bias[col];
#pragma unroll
      for (int r = 0; r < 4; ++r) {
        int row = row0 + wm * 64 + mi * 16 + quad * 4 + r;
        if constexpr (BF16OUT)
          ((ushort_t*)Cv)[(size_t)row * N + col] = f2bf(acc[mi][ni][r] + b);
        else
          ((float*)Cv)[(size_t)row * N + col] = acc[mi][ni][r] + b;
      }
    }
  }
}

// ---------------------------------------------------------------------------
// BC projection, bf16 MFMA: BC[M,32] = XCb[M,1024] @ WxT[32,1024]^T + b_x.
// Same XOR k-chunk swizzle as the big GEMM.
// ---------------------------------------------------------------------------
__global__ __launch_bounds__(128) void bc_mfma_k(
    const ushort_t* __restrict__ A,   // XCb [M,1024]
    const ushort_t* __restrict__ BT,  // WxT [32,1024]
    const float* __restrict__ bias,   // [32]
    float* __restrict__ C) {          // BC [M,32]
  constexpr int K = 1024;
  __shared__ ushort_t As[32 * 32];
  __shared__ ushort_t Bs[32 * 32];

  const int tid = threadIdx.x;
  const int lane = tid & 63;
  const int w = tid >> 6;
  const int row0 = blockIdx.x * 32;
  const int lrow = lane >> 2;
  const int lkc = (lane & 3) ^ ((lrow >> 1) & 3);
  const int frow = lane & 15;
  const int quad = lane >> 4;
  const int sw = (frow >> 1) & 3;

  f32x4 acc[2];
  acc[0] = (f32x4){0.f, 0.f, 0.f, 0.f};
  acc[1] = (f32x4){0.f, 0.f, 0.f, 0.f};

  for (int k0 = 0; k0 < K; k0 += 32) {
    __builtin_amdgcn_global_load_lds(
        (const __attribute__((address_space(1))) u32*)(A + (size_t)(row0 + w * 16 + lrow) * K + k0 + lkc * 8),
        (__attribute__((address_space(3))) u32*)(As + (w * 16) * 32), 16, 0, 0);
    __builtin_amdgcn_global_load_lds(
        (const __attribute__((address_space(1))) u32*)(BT + (size_t)(w * 16 + lrow) * K + k0 + lkc * 8),
        (__attribute__((address_space(3))) u32*)(Bs + (w * 16) * 32), 16, 0, 0);
    __syncthreads();

    s16x8 af = *(const s16x8*)&As[(w * 16 + frow) * 32 + (quad ^ sw) * 8];
    s16x8 bf0 = *(const s16x8*)&Bs[(frow)*32 + (quad ^ sw) * 8];
    s16x8 bf1 = *(const s16x8*)&Bs[(16 + frow) * 32 + (quad ^ sw) * 8];
    acc[0] = __builtin_amdgcn_mfma_f32_16x16x32_bf16(af, bf0, acc[0], 0, 0, 0);
    acc[1] = __builtin_amdgcn_mfma_f32_16x16x32_bf16(af, bf1, acc[1], 0, 0, 0);
    __syncthreads();
  }

#pragma unroll
  for (int ni = 0; ni < 2; ++ni) {
    int col = ni * 16 + frow;
    float b = bias[col];
#pragma unroll
    for (int r = 0; r < 4; ++r) {
      int row = row0 + w * 16 + quad * 4 + r;
      C[(size_t)row * 32 + col] = acc[ni][r] + b;
    }
  }
}

// ---------------------------------------------------------------------------
// Prep: z=0 -> cast x to bf16 (+ zero fs); z=1 -> all 3 weight transposes.
// ---------------------------------------------------------------------------
__global__ __launch_bounds__(256) void prep_k(
    const float* __restrict__ x, ushort_t* __restrict__ Xb,
    float* __restrict__ fs, const float* __restrict__ W_in,
    const float* __restrict__ W_out, const float* __restrict__ W_x,
    ushort_t* __restrict__ WinT, ushort_t* __restrict__ WoutT,
    ushort_t* __restrict__ WxT) {
  constexpr int K = 1024;
  const int tid = threadIdx.x;
  if (blockIdx.z == 0) {
    // cast: 8192 blocks x 1024 floats
    if (blockIdx.x == 0 && blockIdx.y == 0 && tid < 32) fs[tid] = 0.f;
    int i = (blockIdx.y * 64 + blockIdx.x) * 256 + tid;
    float4 v = ((const float4*)x)[i];
    ushort4 o;
    o.x = f2bf(v.x); o.y = f2bf(v.y); o.z = f2bf(v.z); o.w = f2bf(v.w);
    ((ushort4*)Xb)[i] = o;
    return;
  }
  // transposes: by [0,32)->W_in, [32,64)->W_out, [64,96)->W_x
  const float* W;
  ushort_t* WT;
  int N;
  int by = blockIdx.y;
  if (by < 32) {
    W = W_in; WT = WinT; N = 2048;
  } else if (by < 64) {
    if (blockIdx.x >= 32) return;
    W = W_out; WT = WoutT; N = 1024;
    by -= 32;
  } else if (by < 96) {
    if (blockIdx.x >= 1) return;
    W = W_x; WT = WxT; N = 32;
    by -= 64;
  } else {
    return;
  }
  __shared__ float t[32][33];
  int nb = blockIdx.x * 32, kb = by * 32;
  int tx = tid & 31, ty = tid >> 5;  // (32,8)
#pragma unroll
  for (int i = 0; i < 32; i += 8)
    t[ty + i][tx] = W[(size_t)(kb + ty + i) * N + nb + tx];
  __syncthreads();
#pragma unroll
  for (int i = 0; i < 32; i += 8)
    WT[(size_t)(nb + ty + i) * K + kb + tx] = f2bf(t[tx][ty + i]);
}

// ---------------------------------------------------------------------------
// Depthwise causal conv (left pad K-1) + SiLU, all-bf16 I/O.
// 8 d per thread, 16B loads/stores; conv_w staged in LDS (ld=33, conflict-
// free) — R5's scattered global weight loads were a 63us transaction wall.
// ---------------------------------------------------------------------------
__global__ __launch_bounds__(256) void conv_silu_k(
    const ushort_t* __restrict__ XGb, const float* __restrict__ conv_w,
    const float* __restrict__ conv_b, ushort_t* __restrict__ XCb) {
  __shared__ float cw[128 * 33];  // 16.9 KB
  const int tid = threadIdx.x;
#pragma unroll
  for (int j = 0; j < 4; ++j) {
    int d = tid + j * 256;  // float4 index == d (K==4)
    float4 v = ((const float4*)conv_w)[d];
    float* p = &cw[(d >> 3) * 33 + (d & 7) * 4];
    p[0] = v.x; p[1] = v.y; p[2] = v.z; p[3] = v.w;
  }
  __syncthreads();

  int gid = blockIdx.x * 256 + tid;  // over M*128
  int m = gid >> 7;
  int dg = gid & 127;  // d-group
  int d0 = dg * 8;
  int l = m & (LL - 1);
  const float* w = &cw[dg * 33];

  float4 b0 = ((const float4*)conv_b)[dg * 2];
  float4 b1 = ((const float4*)conv_b)[dg * 2 + 1];
  float acc[8] = {b0.x, b0.y, b0.z, b0.w, b1.x, b1.y, b1.z, b1.w};

#pragma unroll
  for (int k = 0; k < KK; ++k) {
    int li = l + k - (KK - 1);
    if (li < 0) continue;
    s16x8 v = *(const s16x8*)(XGb + (size_t)(m + k - (KK - 1)) * 2048 + d0);
#pragma unroll
    for (int j = 0; j < 8; ++j)
      acc[j] += bf2f((ushort_t)v[j]) * w[j * 4 + k];
  }
  ushort_t o[8];
#pragma unroll
  for (int j = 0; j < 8; ++j) {
    float s = acc[j] / (1.f + __expf(-acc[j]));
    o[j] = f2bf(s);
  }
  *(s16x8*)(XCb + (size_t)m * DD + d0) = *(const s16x8*)o;
}

// ---------------------------------------------------------------------------
// Scan phase 1: per-chunk local scan from h=0; store chunk end-state S.
// Grid (B, NC, D/128); 64 threads, 2 d per thread (u32 xc loads).
// ---------------------------------------------------------------------------
__global__ __launch_bounds__(64) void scan_local_k(
    const ushort_t* __restrict__ XCb, const float* __restrict__ BC,
    const float* __restrict__ A_log, float* __restrict__ S) {
  const int b = blockIdx.x, c = blockIdx.y;
  const int tid = threadIdx.x;
  const int d0 = blockIdx.z * 128 + tid * 2;
  const int t0 = c * LC;
  const size_t rowb = (size_t)b * LL;

  __shared__ float bcs[LC * 32];
  {
    const float4* src = (const float4*)(BC + (rowb + t0) * 32);
    float4* dst = (float4*)bcs;
#pragma unroll
    for (int i = 0; i < 8; ++i) dst[tid + i * 64] = src[tid + i * 64];
  }

  float a0[NN], a1[NN], h0[NN], h1[NN];
#pragma unroll
  for (int n = 0; n < NN; ++n) {
    a0[n] = expf(-expf(A_log[d0 * NN + n]));
    a1[n] = expf(-expf(A_log[(d0 + 1) * NN + n]));
    h0[n] = 0.f;
    h1[n] = 0.f;
  }
  __syncthreads();

  const ushort_t* xp = XCb + (rowb + t0) * DD + d0;
  u32 xw = *(const u32*)xp;
  for (int t = 0; t < LC; ++t) {
    u32 xw_n = (t + 1 < LC) ? *(const u32*)(xp + (size_t)(t + 1) * DD) : 0u;
    float x0 = bf2f((ushort_t)(xw & 0xffff));
    float x1 = bf2f((ushort_t)(xw >> 16));
    const float* bp = bcs + t * 32;
#pragma unroll
    for (int n = 0; n < NN; ++n) {
      float bv = bp[n];
      h0[n] = a0[n] * h0[n] + x0 * bv;
      h1[n] = a1[n] * h1[n] + x1 * bv;
    }
    xw = xw_n;
  }
  float* sp = S + (((size_t)(b * NC + c)) * DD + d0) * NN;
#pragma unroll
  for (int n = 0; n < NN; ++n) sp[n] = h0[n];
#pragma unroll
  for (int n = 0; n < NN; ++n) sp[NN + n] = h1[n];
}

// ---------------------------------------------------------------------------
// Scan phase 2: sequential carry over chunks (S -> H0 in place) + fs mean.
// ---------------------------------------------------------------------------
__global__ __launch_bounds__(256) void scan_carry_k(
    float* __restrict__ S, const float* __restrict__ A_log,
    float* __restrict__ fs) {
  const int idx = blockIdx.x * 256 + threadIdx.x;
  const int n = idx & (NN - 1);
  const int d = (idx / NN) & (DD - 1);
  const int b = idx / (NN * DD);

  const float aLC = expf(-(float)LC * expf(A_log[d * NN + n]));
  float h = 0.f;
  for (int c = 0; c < NC; ++c) {
    size_t off = (((size_t)(b * NC + c)) * DD + d) * NN + n;
    float s = S[off];
    S[off] = h;
    h = aLC * h + s;
  }
  __shared__ float red[256];
  red[threadIdx.x] = h * (1.f / (float)DD);
  __syncthreads();
  if (threadIdx.x < NN) {
    float sum = 0.f;
#pragma unroll
    for (int i = 0; i < 16; ++i) sum += red[i * NN + threadIdx.x];
    atomicAdd(&fs[b * NN + threadIdx.x], sum);
  }
}

// ---------------------------------------------------------------------------
// Scan phase 3: replay from H0, y*silu(gate) -> Y1b bf16. 2 d per thread.
// ---------------------------------------------------------------------------
__global__ __launch_bounds__(64) void scan_final_k(
    const ushort_t* __restrict__ XCb, const ushort_t* __restrict__ XGb,
    const float* __restrict__ BC, const float* __restrict__ A_log,
    const float* __restrict__ D_param, const float* __restrict__ H0,
    ushort_t* __restrict__ Y1b) {
  const int b = blockIdx.x, c = blockIdx.y;
  const int tid = threadIdx.x;
  const int d0 = blockIdx.z * 128 + tid * 2;
  const int t0 = c * LC;
  const size_t rowb = (size_t)b * LL;

  __shared__ float bcs[LC * 32];
  {
    const float4* src = (const float4*)(BC + (rowb + t0) * 32);
    float4* dst = (float4*)bcs;
#pragma unroll
    for (int i = 0; i < 8; ++i) dst[tid + i * 64] = src[tid + i * 64];
  }

  float a0[NN], a1[NN], h0[NN], h1[NN];
  const float* hp = H0 + (((size_t)(b * NC + c)) * DD + d0) * NN;
#pragma unroll
  for (int n = 0; n < NN; ++n) {
    a0[n] = expf(-expf(A_log[d0 * NN + n]));
    a1[n] = expf(-expf(A_log[(d0 + 1) * NN + n]));
    h0[n] = hp[n];
    h1[n] = hp[NN + n];
  }
  const float Dp0 = D_param[d0], Dp1 = D_param[d0 + 1];
  __syncthreads();

  const ushort_t* xp = XCb + (rowb + t0) * DD + d0;
  const ushort_t* gp = XGb + (rowb + t0) * 2048 + DD + d0;
  ushort_t* yp = Y1b + (rowb + t0) * DD + d0;
  u32 xw = *(const u32*)xp;
  u32 gw = *(const u32*)gp;
  for (int t = 0; t < LC; ++t) {
    u32 xw_n = 0u, gw_n = 0u;
    if (t + 1 < LC) {
      xw_n = *(const u32*)(xp + (size_t)(t + 1) * DD);
      gw_n = *(const u32*)(gp + (size_t)(t + 1) * 2048);
    }
    float x0 = bf2f((ushort_t)(xw & 0xffff));
    float x1 = bf2f((ushort_t)(xw >> 16));
    float g0 = bf2f((ushort_t)(gw & 0xffff));
    float g1 = bf2f((ushort_t)(gw >> 16));
    float y0 = Dp0 * x0, y1 = Dp1 * x1;
    const float* bp = bcs + t * 32;
#pragma unroll
    for (int n = 0; n < NN; ++n) {
      float bv = bp[n], cv = bp[16 + n];
      h0[n] = a0[n] * h0[n] + x0 * bv;
      h1[n] = a1[n] * h1[n] + x1 * bv;
      y0 += cv * h0[n];
      y1 += cv * h1[n];
    }
    float sg0 = g0 / (1.f + __expf(-g0));
    float sg1 = g1 / (1.f + __expf(-g1));
    u32 outw = (u32)f2bf(y0 * sg0) | ((u32)f2bf(y1 * sg1) << 16);
    *(u32*)(yp + (size_t)t * DD) = outw;
    xw = xw_n;
    gw = gw_n;
  }
}

// ---------------------------------------------------------------------------
extern "C" void kernel_launch(void* const* d_in, const int* in_sizes, int n_in,
                              void* d_out, int out_size, void* d_ws,
                              size_t ws_size, hipStream_t stream) {
  const float* x = (const float*)d_in[0];
  const float* W_in = (const float*)d_in[1];
  const float* b_in = (const float*)d_in[2];
  const float* conv_w = (const float*)d_in[3];
  const float* conv_b = (const float*)d_in[4];
  const float* W_x = (const float*)d_in[5];
  const float* b_x = (const float*)d_in[6];
  const float* A_log = (const float*)d_in[7];
  const float* D_param = (const float*)d_in[8];
  const float* W_out = (const float*)d_in[9];
  const float* b_out = (const float*)d_in[10];
  float* out = (float*)d_out;
  float* fs = out + (size_t)MM * DD;

  // ws layout: f32 regions then bf16 regions (all 16B-aligned)
  float* BC = (float*)d_ws;                    // [8192*32] f32
  float* S = BC + (size_t)MM * 32;             // [2*64*1024*16] f32
  ushort_t* Xb = (ushort_t*)(S + (size_t)BB * NC * DD * NN);  // [8192*1024]
  ushort_t* XGb = Xb + (size_t)MM * DD;        // [8192*2048] bf16
  ushort_t* XCb = XGb + (size_t)MM * 2048;     // [8192*1024] bf16
  ushort_t* Y1b = XCb + (size_t)MM * DD;       // [8192*1024] bf16
  ushort_t* WinT = Y1b + (size_t)MM * DD;      // [2048*1024] bf16
  ushort_t* WoutT = WinT + (size_t)2048 * DD;  // [1024*1024] bf16
  ushort_t* WxT = WoutT + (size_t)DD * DD;     // [32*1024] bf16

  dim3 blk(256);
  // 1. prep: cast x -> bf16 (+ fs zero) and all weight transposes
  prep_k<<<dim3(64, 128, 2), blk, 0, stream>>>(x, Xb, fs, W_in, W_out, W_x,
                                               WinT, WoutT, WxT);
  // 2. in-proj (bf16 MFMA, bf16 out): XGb = x @ W_in + b_in
  gemm_bt_mfma<true><<<dim3((2048 / 128) * (MM / 128)), blk, 0, stream>>>(
      Xb, WinT, b_in, XGb, 2048);
  // 3. conv + silu -> XCb (bf16)
  conv_silu_k<<<dim3((MM * 128) / 256), blk, 0, stream>>>(XGb, conv_w, conv_b,
                                                          XCb);
  // 4. BC proj (bf16 MFMA): BC = x_conv @ W_x + b_x
  bc_mfma_k<<<dim3(MM / 32), dim3(128), 0, stream>>>(XCb, WxT, b_x, BC);
  // 5. scan phase 1
  scan_local_k<<<dim3(BB, NC, DD / 128), dim3(64), 0, stream>>>(XCb, BC, A_log,
                                                                S);
  // 6. carry + final-state mean
  scan_carry_k<<<dim3((BB * DD * NN) / 256), blk, 0, stream>>>(S, A_log, fs);
  // 7. scan phase 3 -> Y1 bf16
  scan_final_k<<<dim3(BB, NC, DD / 128), dim3(64), 0, stream>>>(
      XCb, XGb, BC, A_log, D_param, S, Y1b);
  // 8. out-proj (bf16 MFMA, f32 out): out = Y1 @ W_out + b_out
  gemm_bt_mfma<false><<<dim3((1024 / 128) * (MM / 128)), blk, 0, stream>>>(
      Y1b, WoutT, b_out, out, 1024);
}

// Round 8
// 270.715 us; speedup vs baseline: 1.0372x; 1.0372x over previous
//
#include <hip/hip_runtime.h>
#include <hip/hip_bf16.h>
#include <math.h>

// Problem constants
#define LL 4096
#define DD 1024
#define NN 16
#define KK 4
#define BB 2
#define MM (BB * LL)   // 8192
#define NC 64          // scan chunks
#define LC 64          // chunk length (NC*LC == LL)

typedef unsigned short ushort_t;
typedef short s16x8 __attribute__((ext_vector_type(8)));
typedef float f32x4 __attribute__((ext_vector_type(4)));
typedef unsigned int u32;

__device__ __forceinline__ ushort_t f2bf(float f) {
  __hip_bfloat16 h = __float2bfloat16(f);
  return *reinterpret_cast<ushort_t*>(&h);
}
__device__ __forceinline__ float bf2f(ushort_t u) {
  union { u32 i; float f; } c;
  c.i = ((u32)u) << 16;
  return c.f;
}

// ---------------------------------------------------------------------------
// bf16 MFMA GEMM, B-transposed: C[M,N] = A[M,K] @ BT[N,K]^T + bias, K=1024.
// R8: BK=64 (16 K-iterations instead of 32 -> half the vmcnt(0)+barrier
// drains; 32 MFMA per wave per barrier, AITER-like ratio). 128x128 tile,
// 256 threads (4 waves 2x2), global_load_lds width-16 staging.
// XOR chunk swizzle (R7, verified conflicts->0): LDS slot s of row r holds
// global k-chunk s^(r&7); DMA source chunk = (lane&7)^(lane>>3) keeps the
// lane->LDS mapping contiguous. Reads are 2-way bank aliased (free, m136).
// 2D x-fastest grid (R6: 69.7MB fetch vs R7 1D swizzle 101MB).
// ---------------------------------------------------------------------------
template <bool BF16OUT>
__global__ __launch_bounds__(256) void gemm_bt_mfma(
    const ushort_t* __restrict__ A,   // [M,K] bf16
    const ushort_t* __restrict__ BT,  // [N,K] bf16
    const float* __restrict__ bias,
    void* __restrict__ Cv, int N) {
  constexpr int K = 1024;
  __shared__ ushort_t As[128 * 64];  // 16 KB
  __shared__ ushort_t Bs[128 * 64];  // 16 KB

  const int tid = threadIdx.x;
  const int lane = tid & 63;
  const int w = tid >> 6;            // wave 0..3
  const int wm = w & 1, wn = w >> 1; // 2x2 wave grid over the 128x128 tile
  const int row0 = blockIdx.y * 128;
  const int col0 = blockIdx.x * 128;

  const int lrow8 = lane >> 3;             // 0..7: row within 8-row DMA group
  const int lkc = (lane & 7) ^ lrow8;      // swizzled source k-chunk (8B elems)

  f32x4 acc[4][4];
#pragma unroll
  for (int i = 0; i < 4; ++i)
#pragma unroll
    for (int j = 0; j < 4; ++j) acc[i][j] = (f32x4){0.f, 0.f, 0.f, 0.f};

  const int frow = lane & 15;
  const int quad = lane >> 4;
  const int r7 = frow & 7;  // == row&7 for all fragment rows (offsets %8==0)

  for (int k0 = 0; k0 < K; k0 += 64) {
#pragma unroll
    for (int it = 0; it < 4; ++it) {
      int r = it * 32 + w * 8;  // wave-uniform 8-row group
      __builtin_amdgcn_global_load_lds(
          (const __attribute__((address_space(1))) u32*)(A + (size_t)(row0 + r + lrow8) * K + k0 + lkc * 8),
          (__attribute__((address_space(3))) u32*)(As + r * 64), 16, 0, 0);
      __builtin_amdgcn_global_load_lds(
          (const __attribute__((address_space(1))) u32*)(BT + (size_t)(col0 + r + lrow8) * K + k0 + lkc * 8),
          (__attribute__((address_space(3))) u32*)(Bs + r * 64), 16, 0, 0);
    }
    __syncthreads();

#pragma unroll
    for (int half = 0; half < 2; ++half) {
      s16x8 af[4], bf[4];
#pragma unroll
      for (int mi = 0; mi < 4; ++mi)
        af[mi] = *(const s16x8*)&As[(wm * 64 + mi * 16 + frow) * 64 +
                                    (((half * 4 + quad) ^ r7) * 8)];
#pragma unroll
      for (int ni = 0; ni < 4; ++ni)
        bf[ni] = *(const s16x8*)&Bs[(wn * 64 + ni * 16 + frow) * 64 +
                                    (((half * 4 + quad) ^ r7) * 8)];
#pragma unroll
      for (int mi = 0; mi < 4; ++mi)
#pragma unroll
        for (int ni = 0; ni < 4; ++ni)
          acc[mi][ni] = __builtin_amdgcn_mfma_f32_16x16x32_bf16(
              af[mi], bf[ni], acc[mi][ni], 0, 0, 0);
    }
    __syncthreads();
  }

  // Epilogue: C/D layout col=lane&15, row=quad*4+reg
#pragma unroll
  for (int mi = 0; mi < 4; ++mi) {
#pragma unroll
    for (int ni = 0; ni < 4; ++ni) {
      int col = col0 + wn * 64 + ni * 16 + frow;
      float b = bias[col];
#pragma unroll
      for (int r = 0; r < 4; ++r) {
        int row = row0 + wm * 64 + mi * 16 + quad * 4 + r;
        if constexpr (BF16OUT)
          ((ushort_t*)Cv)[(size_t)row * N + col] = f2bf(acc[mi][ni][r] + b);
        else
          ((float*)Cv)[(size_t)row * N + col] = acc[mi][ni][r] + b;
      }
    }
  }
}

// ---------------------------------------------------------------------------
// BC projection, bf16 MFMA: BC[M,32] = XCb[M,1024] @ WxT[32,1024]^T + b_x.
// BK=32 with the R7 4-chunk XOR swizzle.
// ---------------------------------------------------------------------------
__global__ __launch_bounds__(128) void bc_mfma_k(
    const ushort_t* __restrict__ A,   // XCb [M,1024]
    const ushort_t* __restrict__ BT,  // WxT [32,1024]
    const float* __restrict__ bias,   // [32]
    float* __restrict__ C) {          // BC [M,32]
  constexpr int K = 1024;
  __shared__ ushort_t As[32 * 32];
  __shared__ ushort_t Bs[32 * 32];

  const int tid = threadIdx.x;
  const int lane = tid & 63;
  const int w = tid >> 6;
  const int row0 = blockIdx.x * 32;
  const int lrow = lane >> 2;
  const int lkc = (lane & 3) ^ ((lrow >> 1) & 3);
  const int frow = lane & 15;
  const int quad = lane >> 4;
  const int sw = (frow >> 1) & 3;

  f32x4 acc[2];
  acc[0] = (f32x4){0.f, 0.f, 0.f, 0.f};
  acc[1] = (f32x4){0.f, 0.f, 0.f, 0.f};

  for (int k0 = 0; k0 < K; k0 += 32) {
    __builtin_amdgcn_global_load_lds(
        (const __attribute__((address_space(1))) u32*)(A + (size_t)(row0 + w * 16 + lrow) * K + k0 + lkc * 8),
        (__attribute__((address_space(3))) u32*)(As + (w * 16) * 32), 16, 0, 0);
    __builtin_amdgcn_global_load_lds(
        (const __attribute__((address_space(1))) u32*)(BT + (size_t)(w * 16 + lrow) * K + k0 + lkc * 8),
        (__attribute__((address_space(3))) u32*)(Bs + (w * 16) * 32), 16, 0, 0);
    __syncthreads();

    s16x8 af = *(const s16x8*)&As[(w * 16 + frow) * 32 + (quad ^ sw) * 8];
    s16x8 bf0 = *(const s16x8*)&Bs[(frow)*32 + (quad ^ sw) * 8];
    s16x8 bf1 = *(const s16x8*)&Bs[(16 + frow) * 32 + (quad ^ sw) * 8];
    acc[0] = __builtin_amdgcn_mfma_f32_16x16x32_bf16(af, bf0, acc[0], 0, 0, 0);
    acc[1] = __builtin_amdgcn_mfma_f32_16x16x32_bf16(af, bf1, acc[1], 0, 0, 0);
    __syncthreads();
  }

#pragma unroll
  for (int ni = 0; ni < 2; ++ni) {
    int col = ni * 16 + frow;
    float b = bias[col];
#pragma unroll
    for (int r = 0; r < 4; ++r) {
      int row = row0 + w * 16 + quad * 4 + r;
      C[(size_t)row * 32 + col] = acc[ni][r] + b;
    }
  }
}

// ---------------------------------------------------------------------------
// Prep: z=0 -> cast x to bf16 (+ zero fs); z=1 -> all 3 weight transposes.
// ---------------------------------------------------------------------------
__global__ __launch_bounds__(256) void prep_k(
    const float* __restrict__ x, ushort_t* __restrict__ Xb,
    float* __restrict__ fs, const float* __restrict__ W_in,
    const float* __restrict__ W_out, const float* __restrict__ W_x,
    ushort_t* __restrict__ WinT, ushort_t* __restrict__ WoutT,
    ushort_t* __restrict__ WxT) {
  constexpr int K = 1024;
  const int tid = threadIdx.x;
  if (blockIdx.z == 0) {
    if (blockIdx.x == 0 && blockIdx.y == 0 && tid < 32) fs[tid] = 0.f;
    int i = (blockIdx.y * 64 + blockIdx.x) * 256 + tid;
    float4 v = ((const float4*)x)[i];
    ushort4 o;
    o.x = f2bf(v.x); o.y = f2bf(v.y); o.z = f2bf(v.z); o.w = f2bf(v.w);
    ((ushort4*)Xb)[i] = o;
    return;
  }
  const float* W;
  ushort_t* WT;
  int N;
  int by = blockIdx.y;
  if (by < 32) {
    W = W_in; WT = WinT; N = 2048;
  } else if (by < 64) {
    if (blockIdx.x >= 32) return;
    W = W_out; WT = WoutT; N = 1024;
    by -= 32;
  } else if (by < 96) {
    if (blockIdx.x >= 1) return;
    W = W_x; WT = WxT; N = 32;
    by -= 64;
  } else {
    return;
  }
  __shared__ float t[32][33];
  int nb = blockIdx.x * 32, kb = by * 32;
  int tx = tid & 31, ty = tid >> 5;  // (32,8)
#pragma unroll
  for (int i = 0; i < 32; i += 8)
    t[ty + i][tx] = W[(size_t)(kb + ty + i) * N + nb + tx];
  __syncthreads();
#pragma unroll
  for (int i = 0; i < 32; i += 8)
    WT[(size_t)(nb + ty + i) * K + kb + tx] = f2bf(t[tx][ty + i]);
}

// ---------------------------------------------------------------------------
// Depthwise causal conv (left pad K-1) + SiLU, all-bf16 I/O.
// 8 d per thread, 16B loads/stores; conv_w staged in LDS (ld=33, conflict-
// free) — R5's scattered global weight loads were a 63us transaction wall.
// ---------------------------------------------------------------------------
__global__ __launch_bounds__(256) void conv_silu_k(
    const ushort_t* __restrict__ XGb, const float* __restrict__ conv_w,
    const float* __restrict__ conv_b, ushort_t* __restrict__ XCb) {
  __shared__ float cw[128 * 33];  // 16.9 KB
  const int tid = threadIdx.x;
#pragma unroll
  for (int j = 0; j < 4; ++j) {
    int d = tid + j * 256;  // float4 index == d (K==4)
    float4 v = ((const float4*)conv_w)[d];
    float* p = &cw[(d >> 3) * 33 + (d & 7) * 4];
    p[0] = v.x; p[1] = v.y; p[2] = v.z; p[3] = v.w;
  }
  __syncthreads();

  int gid = blockIdx.x * 256 + tid;  // over M*128
  int m = gid >> 7;
  int dg = gid & 127;  // d-group
  int d0 = dg * 8;
  int l = m & (LL - 1);
  const float* w = &cw[dg * 33];

  float4 b0 = ((const float4*)conv_b)[dg * 2];
  float4 b1 = ((const float4*)conv_b)[dg * 2 + 1];
  float acc[8] = {b0.x, b0.y, b0.z, b0.w, b1.x, b1.y, b1.z, b1.w};

#pragma unroll
  for (int k = 0; k < KK; ++k) {
    int li = l + k - (KK - 1);
    if (li < 0) continue;
    s16x8 v = *(const s16x8*)(XGb + (size_t)(m + k - (KK - 1)) * 2048 + d0);
#pragma unroll
    for (int j = 0; j < 8; ++j)
      acc[j] += bf2f((ushort_t)v[j]) * w[j * 4 + k];
  }
  ushort_t o[8];
#pragma unroll
  for (int j = 0; j < 8; ++j) {
    float s = acc[j] / (1.f + __expf(-acc[j]));
    o[j] = f2bf(s);
  }
  *(s16x8*)(XCb + (size_t)m * DD + d0) = *(const s16x8*)o;
}

// ---------------------------------------------------------------------------
// Scan phase 1: per-chunk local scan from h=0; store chunk end-state S.
// Grid (B, NC, D/128); 64 threads, 2 d per thread (u32 xc loads).
// ---------------------------------------------------------------------------
__global__ __launch_bounds__(64) void scan_local_k(
    const ushort_t* __restrict__ XCb, const float* __restrict__ BC,
    const float* __restrict__ A_log, float* __restrict__ S) {
  const int b = blockIdx.x, c = blockIdx.y;
  const int tid = threadIdx.x;
  const int d0 = blockIdx.z * 128 + tid * 2;
  const int t0 = c * LC;
  const size_t rowb = (size_t)b * LL;

  __shared__ float bcs[LC * 32];
  {
    const float4* src = (const float4*)(BC + (rowb + t0) * 32);
    float4* dst = (float4*)bcs;
#pragma unroll
    for (int i = 0; i < 8; ++i) dst[tid + i * 64] = src[tid + i * 64];
  }

  float a0[NN], a1[NN], h0[NN], h1[NN];
#pragma unroll
  for (int n = 0; n < NN; ++n) {
    a0[n] = expf(-expf(A_log[d0 * NN + n]));
    a1[n] = expf(-expf(A_log[(d0 + 1) * NN + n]));
    h0[n] = 0.f;
    h1[n] = 0.f;
  }
  __syncthreads();

  const ushort_t* xp = XCb + (rowb + t0) * DD + d0;
  u32 xw = *(const u32*)xp;
  for (int t = 0; t < LC; ++t) {
    u32 xw_n = (t + 1 < LC) ? *(const u32*)(xp + (size_t)(t + 1) * DD) : 0u;
    float x0 = bf2f((ushort_t)(xw & 0xffff));
    float x1 = bf2f((ushort_t)(xw >> 16));
    const float* bp = bcs + t * 32;
#pragma unroll
    for (int n = 0; n < NN; ++n) {
      float bv = bp[n];
      h0[n] = a0[n] * h0[n] + x0 * bv;
      h1[n] = a1[n] * h1[n] + x1 * bv;
    }
    xw = xw_n;
  }
  float* sp = S + (((size_t)(b * NC + c)) * DD + d0) * NN;
#pragma unroll
  for (int n = 0; n < NN; ++n) sp[n] = h0[n];
#pragma unroll
  for (int n = 0; n < NN; ++n) sp[NN + n] = h1[n];
}

// ---------------------------------------------------------------------------
// Scan phase 2: sequential carry over chunks (S -> H0 in place) + fs mean.
// ---------------------------------------------------------------------------
__global__ __launch_bounds__(256) void scan_carry_k(
    float* __restrict__ S, const float* __restrict__ A_log,
    float* __restrict__ fs) {
  const int idx = blockIdx.x * 256 + threadIdx.x;
  const int n = idx & (NN - 1);
  const int d = (idx / NN) & (DD - 1);
  const int b = idx / (NN * DD);

  const float aLC = expf(-(float)LC * expf(A_log[d * NN + n]));
  float h = 0.f;
  for (int c = 0; c < NC; ++c) {
    size_t off = (((size_t)(b * NC + c)) * DD + d) * NN + n;
    float s = S[off];
    S[off] = h;
    h = aLC * h + s;
  }
  __shared__ float red[256];
  red[threadIdx.x] = h * (1.f / (float)DD);
  __syncthreads();
  if (threadIdx.x < NN) {
    float sum = 0.f;
#pragma unroll
    for (int i = 0; i < 16; ++i) sum += red[i * NN + threadIdx.x];
    atomicAdd(&fs[b * NN + threadIdx.x], sum);
  }
}

// ---------------------------------------------------------------------------
// Scan phase 3: replay from H0, y*silu(gate) -> Y1b bf16. 2 d per thread.
// ---------------------------------------------------------------------------
__global__ __launch_bounds__(64) void scan_final_k(
    const ushort_t* __restrict__ XCb, const ushort_t* __restrict__ XGb,
    const float* __restrict__ BC, const float* __restrict__ A_log,
    const float* __restrict__ D_param, const float* __restrict__ H0,
    ushort_t* __restrict__ Y1b) {
  const int b = blockIdx.x, c = blockIdx.y;
  const int tid = threadIdx.x;
  const int d0 = blockIdx.z * 128 + tid * 2;
  const int t0 = c * LC;
  const size_t rowb = (size_t)b * LL;

  __shared__ float bcs[LC * 32];
  {
    const float4* src = (const float4*)(BC + (rowb + t0) * 32);
    float4* dst = (float4*)bcs;
#pragma unroll
    for (int i = 0; i < 8; ++i) dst[tid + i * 64] = src[tid + i * 64];
  }

  float a0[NN], a1[NN], h0[NN], h1[NN];
  const float* hp = H0 + (((size_t)(b * NC + c)) * DD + d0) * NN;
#pragma unroll
  for (int n = 0; n < NN; ++n) {
    a0[n] = expf(-expf(A_log[d0 * NN + n]));
    a1[n] = expf(-expf(A_log[(d0 + 1) * NN + n]));
    h0[n] = hp[n];
    h1[n] = hp[NN + n];
  }
  const float Dp0 = D_param[d0], Dp1 = D_param[d0 + 1];
  __syncthreads();

  const ushort_t* xp = XCb + (rowb + t0) * DD + d0;
  const ushort_t* gp = XGb + (rowb + t0) * 2048 + DD + d0;
  ushort_t* yp = Y1b + (rowb + t0) * DD + d0;
  u32 xw = *(const u32*)xp;
  u32 gw = *(const u32*)gp;
  for (int t = 0; t < LC; ++t) {
    u32 xw_n = 0u, gw_n = 0u;
    if (t + 1 < LC) {
      xw_n = *(const u32*)(xp + (size_t)(t + 1) * DD);
      gw_n = *(const u32*)(gp + (size_t)(t + 1) * 2048);
    }
    float x0 = bf2f((ushort_t)(xw & 0xffff));
    float x1 = bf2f((ushort_t)(xw >> 16));
    float g0 = bf2f((ushort_t)(gw & 0xffff));
    float g1 = bf2f((ushort_t)(gw >> 16));
    float y0 = Dp0 * x0, y1 = Dp1 * x1;
    const float* bp = bcs + t * 32;
#pragma unroll
    for (int n = 0; n < NN; ++n) {
      float bv = bp[n], cv = bp[16 + n];
      h0[n] = a0[n] * h0[n] + x0 * bv;
      h1[n] = a1[n] * h1[n] + x1 * bv;
      y0 += cv * h0[n];
      y1 += cv * h1[n];
    }
    float sg0 = g0 / (1.f + __expf(-g0));
    float sg1 = g1 / (1.f + __expf(-g1));
    u32 outw = (u32)f2bf(y0 * sg0) | ((u32)f2bf(y1 * sg1) << 16);
    *(u32*)(yp + (size_t)t * DD) = outw;
    xw = xw_n;
    gw = gw_n;
  }
}

// ---------------------------------------------------------------------------
extern "C" void kernel_launch(void* const* d_in, const int* in_sizes, int n_in,
                              void* d_out, int out_size, void* d_ws,
                              size_t ws_size, hipStream_t stream) {
  const float* x = (const float*)d_in[0];
  const float* W_in = (const float*)d_in[1];
  const float* b_in = (const float*)d_in[2];
  const float* conv_w = (const float*)d_in[3];
  const float* conv_b = (const float*)d_in[4];
  const float* W_x = (const float*)d_in[5];
  const float* b_x = (const float*)d_in[6];
  const float* A_log = (const float*)d_in[7];
  const float* D_param = (const float*)d_in[8];
  const float* W_out = (const float*)d_in[9];
  const float* b_out = (const float*)d_in[10];
  float* out = (float*)d_out;
  float* fs = out + (size_t)MM * DD;

  // ws layout: f32 regions then bf16 regions (all 16B-aligned)
  float* BC = (float*)d_ws;                    // [8192*32] f32
  float* S = BC + (size_t)MM * 32;             // [2*64*1024*16] f32
  ushort_t* Xb = (ushort_t*)(S + (size_t)BB * NC * DD * NN);  // [8192*1024]
  ushort_t* XGb = Xb + (size_t)MM * DD;        // [8192*2048] bf16
  ushort_t* XCb = XGb + (size_t)MM * 2048;     // [8192*1024] bf16
  ushort_t* Y1b = XCb + (size_t)MM * DD;       // [8192*1024] bf16
  ushort_t* WinT = Y1b + (size_t)MM * DD;      // [2048*1024] bf16
  ushort_t* WoutT = WinT + (size_t)2048 * DD;  // [1024*1024] bf16
  ushort_t* WxT = WoutT + (size_t)DD * DD;     // [32*1024] bf16

  dim3 blk(256);
  // 1. prep: cast x -> bf16 (+ fs zero) and all weight transposes
  prep_k<<<dim3(64, 128, 2), blk, 0, stream>>>(x, Xb, fs, W_in, W_out, W_x,
                                               WinT, WoutT, WxT);
  // 2. in-proj (bf16 MFMA, bf16 out): XGb = x @ W_in + b_in
  gemm_bt_mfma<true><<<dim3(2048 / 128, MM / 128), blk, 0, stream>>>(
      Xb, WinT, b_in, XGb, 2048);
  // 3. conv + silu -> XCb (bf16)
  conv_silu_k<<<dim3((MM * 128) / 256), blk, 0, stream>>>(XGb, conv_w, conv_b,
                                                          XCb);
  // 4. BC proj (bf16 MFMA): BC = x_conv @ W_x + b_x
  bc_mfma_k<<<dim3(MM / 32), dim3(128), 0, stream>>>(XCb, WxT, b_x, BC);
  // 5. scan phase 1
  scan_local_k<<<dim3(BB, NC, DD / 128), dim3(64), 0, stream>>>(XCb, BC, A_log,
                                                                S);
  // 6. carry + final-state mean
  scan_carry_k<<<dim3((BB * DD * NN) / 256), blk, 0, stream>>>(S, A_log, fs);
  // 7. scan phase 3 -> Y1 bf16
  scan_final_k<<<dim3(BB, NC, DD / 128), dim3(64), 0, stream>>>(
      XCb, XGb, BC, A_log, D_param, S, Y1b);
  // 8. out-proj (bf16 MFMA, f32 out): out = Y1 @ W_out + b_out
  gemm_bt_mfma<false><<<dim3(1024 / 128, MM / 128), blk, 0, stream>>>(
      Y1b, WoutT, b_out, out, 1024);
}

// Round 9
// 249.684 us; speedup vs baseline: 1.1245x; 1.0842x over previous
//
#include <hip/hip_runtime.h>
#include <hip/hip_bf16.h>
#include <math.h>

// Problem constants
#define LL 4096
#define DD 1024
#define NN 16
#define KK 4
#define BB 2
#define MM (BB * LL)   // 8192
#define NC 128         // scan chunks
#define LC 32          // chunk length (NC*LC == LL)

typedef unsigned short ushort_t;
typedef short s16x8 __attribute__((ext_vector_type(8)));
typedef float f32x4 __attribute__((ext_vector_type(4)));
typedef unsigned int u32;

__device__ __forceinline__ ushort_t f2bf(float f) {
  __hip_bfloat16 h = __float2bfloat16(f);
  return *reinterpret_cast<ushort_t*>(&h);
}
__device__ __forceinline__ float bf2f(ushort_t u) {
  union { u32 i; float f; } c;
  c.i = ((u32)u) << 16;
  return c.f;
}

// ---------------------------------------------------------------------------
// bf16 MFMA GEMM, B-transposed (R8 structure, unchanged): 128x128 tile,
// BK=64, XOR chunk swizzle (conflicts==0 verified R7/R8), 2D x-fastest grid.
// ---------------------------------------------------------------------------
template <bool BF16OUT>
__global__ __launch_bounds__(256) void gemm_bt_mfma(
    const ushort_t* __restrict__ A,   // [M,K] bf16
    const ushort_t* __restrict__ BT,  // [N,K] bf16
    const float* __restrict__ bias,
    void* __restrict__ Cv, int N) {
  constexpr int K = 1024;
  __shared__ ushort_t As[128 * 64];  // 16 KB
  __shared__ ushort_t Bs[128 * 64];  // 16 KB

  const int tid = threadIdx.x;
  const int lane = tid & 63;
  const int w = tid >> 6;
  const int wm = w & 1, wn = w >> 1;
  const int row0 = blockIdx.y * 128;
  const int col0 = blockIdx.x * 128;

  const int lrow8 = lane >> 3;
  const int lkc = (lane & 7) ^ lrow8;

  f32x4 acc[4][4];
#pragma unroll
  for (int i = 0; i < 4; ++i)
#pragma unroll
    for (int j = 0; j < 4; ++j) acc[i][j] = (f32x4){0.f, 0.f, 0.f, 0.f};

  const int frow = lane & 15;
  const int quad = lane >> 4;
  const int r7 = frow & 7;

  for (int k0 = 0; k0 < K; k0 += 64) {
#pragma unroll
    for (int it = 0; it < 4; ++it) {
      int r = it * 32 + w * 8;
      __builtin_amdgcn_global_load_lds(
          (const __attribute__((address_space(1))) u32*)(A + (size_t)(row0 + r + lrow8) * K + k0 + lkc * 8),
          (__attribute__((address_space(3))) u32*)(As + r * 64), 16, 0, 0);
      __builtin_amdgcn_global_load_lds(
          (const __attribute__((address_space(1))) u32*)(BT + (size_t)(col0 + r + lrow8) * K + k0 + lkc * 8),
          (__attribute__((address_space(3))) u32*)(Bs + r * 64), 16, 0, 0);
    }
    __syncthreads();

#pragma unroll
    for (int half = 0; half < 2; ++half) {
      s16x8 af[4], bf[4];
#pragma unroll
      for (int mi = 0; mi < 4; ++mi)
        af[mi] = *(const s16x8*)&As[(wm * 64 + mi * 16 + frow) * 64 +
                                    (((half * 4 + quad) ^ r7) * 8)];
#pragma unroll
      for (int ni = 0; ni < 4; ++ni)
        bf[ni] = *(const s16x8*)&Bs[(wn * 64 + ni * 16 + frow) * 64 +
                                    (((half * 4 + quad) ^ r7) * 8)];
#pragma unroll
      for (int mi = 0; mi < 4; ++mi)
#pragma unroll
        for (int ni = 0; ni < 4; ++ni)
          acc[mi][ni] = __builtin_amdgcn_mfma_f32_16x16x32_bf16(
              af[mi], bf[ni], acc[mi][ni], 0, 0, 0);
    }
    __syncthreads();
  }

#pragma unroll
  for (int mi = 0; mi < 4; ++mi) {
#pragma unroll
    for (int ni = 0; ni < 4; ++ni) {
      int col = col0 + wn * 64 + ni * 16 + frow;
      float b = bias[col];
#pragma unroll
      for (int r = 0; r < 4; ++r) {
        int row = row0 + wm * 64 + mi * 16 + quad * 4 + r;
        if constexpr (BF16OUT)
          ((ushort_t*)Cv)[(size_t)row * N + col] = f2bf(acc[mi][ni][r] + b);
        else
          ((float*)Cv)[(size_t)row * N + col] = acc[mi][ni][r] + b;
      }
    }
  }
}

// ---------------------------------------------------------------------------
// BC projection, bf16 MFMA (unchanged R7 structure).
// ---------------------------------------------------------------------------
__global__ __launch_bounds__(128) void bc_mfma_k(
    const ushort_t* __restrict__ A, const ushort_t* __restrict__ BT,
    const float* __restrict__ bias, float* __restrict__ C) {
  constexpr int K = 1024;
  __shared__ ushort_t As[32 * 32];
  __shared__ ushort_t Bs[32 * 32];

  const int tid = threadIdx.x;
  const int lane = tid & 63;
  const int w = tid >> 6;
  const int row0 = blockIdx.x * 32;
  const int lrow = lane >> 2;
  const int lkc = (lane & 3) ^ ((lrow >> 1) & 3);
  const int frow = lane & 15;
  const int quad = lane >> 4;
  const int sw = (frow >> 1) & 3;

  f32x4 acc[2];
  acc[0] = (f32x4){0.f, 0.f, 0.f, 0.f};
  acc[1] = (f32x4){0.f, 0.f, 0.f, 0.f};

  for (int k0 = 0; k0 < K; k0 += 32) {
    __builtin_amdgcn_global_load_lds(
        (const __attribute__((address_space(1))) u32*)(A + (size_t)(row0 + w * 16 + lrow) * K + k0 + lkc * 8),
        (__attribute__((address_space(3))) u32*)(As + (w * 16) * 32), 16, 0, 0);
    __builtin_amdgcn_global_load_lds(
        (const __attribute__((address_space(1))) u32*)(BT + (size_t)(w * 16 + lrow) * K + k0 + lkc * 8),
        (__attribute__((address_space(3))) u32*)(Bs + (w * 16) * 32), 16, 0, 0);
    __syncthreads();

    s16x8 af = *(const s16x8*)&As[(w * 16 + frow) * 32 + (quad ^ sw) * 8];
    s16x8 bf0 = *(const s16x8*)&Bs[(frow)*32 + (quad ^ sw) * 8];
    s16x8 bf1 = *(const s16x8*)&Bs[(16 + frow) * 32 + (quad ^ sw) * 8];
    acc[0] = __builtin_amdgcn_mfma_f32_16x16x32_bf16(af, bf0, acc[0], 0, 0, 0);
    acc[1] = __builtin_amdgcn_mfma_f32_16x16x32_bf16(af, bf1, acc[1], 0, 0, 0);
    __syncthreads();
  }

#pragma unroll
  for (int ni = 0; ni < 2; ++ni) {
    int col = ni * 16 + frow;
    float b = bias[col];
#pragma unroll
    for (int r = 0; r < 4; ++r) {
      int row = row0 + w * 16 + quad * 4 + r;
      C[(size_t)row * 32 + col] = acc[ni][r] + b;
    }
  }
}

// ---------------------------------------------------------------------------
// Prep: z=0 -> cast x to bf16 (+ zero fs); z=1 -> weight transposes and
// (by in [96,104)) the precomputed decay tables:
//   Adis[d*16+n] = exp(-exp(A_log)),  ALC[d*16+n] = exp(-LC*exp(A_log)).
// ---------------------------------------------------------------------------
__global__ __launch_bounds__(256) void prep_k(
    const float* __restrict__ x, ushort_t* __restrict__ Xb,
    float* __restrict__ fs, const float* __restrict__ W_in,
    const float* __restrict__ W_out, const float* __restrict__ W_x,
    ushort_t* __restrict__ WinT, ushort_t* __restrict__ WoutT,
    ushort_t* __restrict__ WxT, const float* __restrict__ A_log,
    float* __restrict__ Adis, float* __restrict__ ALC) {
  constexpr int K = 1024;
  const int tid = threadIdx.x;
  if (blockIdx.z == 0) {
    if (blockIdx.x == 0 && blockIdx.y == 0 && tid < 32) fs[tid] = 0.f;
    int i = (blockIdx.y * 64 + blockIdx.x) * 256 + tid;
    float4 v = ((const float4*)x)[i];
    ushort4 o;
    o.x = f2bf(v.x); o.y = f2bf(v.y); o.z = f2bf(v.z); o.w = f2bf(v.w);
    ((ushort4*)Xb)[i] = o;
    return;
  }
  int by = blockIdx.y;
  if (by >= 96) {
    // decay tables: 8 blocks (by 96..103) x 2048 elements
    if (by >= 104 || blockIdx.x != 0) return;
    int base = (by - 96) * 2048 + tid * 8;
#pragma unroll
    for (int j = 0; j < 8; ++j) {
      float e = __expf(A_log[base + j]);
      Adis[base + j] = __expf(-e);
      ALC[base + j] = __expf(-(float)LC * e);
    }
    return;
  }
  const float* W;
  ushort_t* WT;
  int N;
  if (by < 32) {
    W = W_in; WT = WinT; N = 2048;
  } else if (by < 64) {
    if (blockIdx.x >= 32) return;
    W = W_out; WT = WoutT; N = 1024;
    by -= 32;
  } else {
    if (blockIdx.x >= 1) return;
    W = W_x; WT = WxT; N = 32;
    by -= 64;
  }
  __shared__ float t[32][33];
  int nb = blockIdx.x * 32, kb = by * 32;
  int tx = tid & 31, ty = tid >> 5;  // (32,8)
#pragma unroll
  for (int i = 0; i < 32; i += 8)
    t[ty + i][tx] = W[(size_t)(kb + ty + i) * N + nb + tx];
  __syncthreads();
#pragma unroll
  for (int i = 0; i < 32; i += 8)
    WT[(size_t)(nb + ty + i) * K + kb + tx] = f2bf(t[tx][ty + i]);
}

// ---------------------------------------------------------------------------
// Depthwise causal conv + SiLU, all-bf16 I/O (unchanged R6 structure).
// ---------------------------------------------------------------------------
__global__ __launch_bounds__(256) void conv_silu_k(
    const ushort_t* __restrict__ XGb, const float* __restrict__ conv_w,
    const float* __restrict__ conv_b, ushort_t* __restrict__ XCb) {
  __shared__ float cw[128 * 33];
  const int tid = threadIdx.x;
#pragma unroll
  for (int j = 0; j < 4; ++j) {
    int d = tid + j * 256;
    float4 v = ((const float4*)conv_w)[d];
    float* p = &cw[(d >> 3) * 33 + (d & 7) * 4];
    p[0] = v.x; p[1] = v.y; p[2] = v.z; p[3] = v.w;
  }
  __syncthreads();

  int gid = blockIdx.x * 256 + tid;
  int m = gid >> 7;
  int dg = gid & 127;
  int d0 = dg * 8;
  int l = m & (LL - 1);
  const float* w = &cw[dg * 33];

  float4 b0 = ((const float4*)conv_b)[dg * 2];
  float4 b1 = ((const float4*)conv_b)[dg * 2 + 1];
  float acc[8] = {b0.x, b0.y, b0.z, b0.w, b1.x, b1.y, b1.z, b1.w};

#pragma unroll
  for (int k = 0; k < KK; ++k) {
    int li = l + k - (KK - 1);
    if (li < 0) continue;
    s16x8 v = *(const s16x8*)(XGb + (size_t)(m + k - (KK - 1)) * 2048 + d0);
#pragma unroll
    for (int j = 0; j < 8; ++j)
      acc[j] += bf2f((ushort_t)v[j]) * w[j * 4 + k];
  }
  ushort_t o[8];
#pragma unroll
  for (int j = 0; j < 8; ++j) {
    float s = acc[j] / (1.f + __expf(-acc[j]));
    o[j] = f2bf(s);
  }
  *(s16x8*)(XCb + (size_t)m * DD + d0) = *(const s16x8*)o;
}

// ---------------------------------------------------------------------------
// Scan phase 1: per-chunk local scan from h=0; store chunk end-state S.
// R9: 256-thread blocks = 4 waves, each wave owns one chunk with a PRIVATE
// LDS slice -> zero barriers. Grid (B, NC/4, D/128); 2 d per thread.
// S layout [b][c][n][d] -> all accesses lane-consecutive.
// ---------------------------------------------------------------------------
__global__ __launch_bounds__(256) void scan_local_k(
    const ushort_t* __restrict__ XCb, const float* __restrict__ BC,
    const float* __restrict__ Adis, float* __restrict__ S) {
  const int b = blockIdx.x;
  const int w = threadIdx.x >> 6;
  const int lane = threadIdx.x & 63;
  const int c = blockIdx.y * 4 + w;
  const int d0 = blockIdx.z * 128 + lane * 2;
  const int t0 = c * LC;
  const size_t rowb = (size_t)b * LL;

  __shared__ float bcs_all[4][LC * 32];
  float* bcs = bcs_all[w];
  {
    const float4* src = (const float4*)(BC + (rowb + t0) * 32);
    float4* dst = (float4*)bcs;
#pragma unroll
    for (int i = 0; i < 4; ++i) dst[lane + i * 64] = src[lane + i * 64];
  }
  f32x4 av[8];
#pragma unroll
  for (int i = 0; i < 8; ++i) av[i] = *(const f32x4*)(Adis + d0 * 16 + i * 4);

  float h0[NN], h1[NN];
#pragma unroll
  for (int n = 0; n < NN; ++n) { h0[n] = 0.f; h1[n] = 0.f; }

  const ushort_t* xp = XCb + (rowb + t0) * DD + d0;
  u32 xw = *(const u32*)xp;
  for (int t = 0; t < LC; ++t) {
    u32 xw_n = (t + 1 < LC) ? *(const u32*)(xp + (size_t)(t + 1) * DD) : 0u;
    float x0 = bf2f((ushort_t)(xw & 0xffff));
    float x1 = bf2f((ushort_t)(xw >> 16));
    const float* bp = bcs + t * 32;
#pragma unroll
    for (int n = 0; n < NN; ++n) {
      float bv = bp[n];
      h0[n] = av[n >> 2][n & 3] * h0[n] + x0 * bv;
      h1[n] = av[4 + (n >> 2)][n & 3] * h1[n] + x1 * bv;
    }
    xw = xw_n;
  }
  float* sp = S + ((size_t)(b * NC + c) * NN) * DD + d0;
#pragma unroll
  for (int n = 0; n < NN; ++n) {
    float2 v = {h0[n], h1[n]};
    *(float2*)(sp + (size_t)n * DD) = v;
  }
}

// ---------------------------------------------------------------------------
// Scan phase 2: sequential carry over chunks (S -> H0 in place) + fs mean.
// d-fastest thread mapping -> coalesced S access at every step.
// ---------------------------------------------------------------------------
__global__ __launch_bounds__(256) void scan_carry_k(
    float* __restrict__ S, const float* __restrict__ ALC,
    float* __restrict__ fs) {
  const int idx = blockIdx.x * 256 + threadIdx.x;
  const int d = idx & (DD - 1);
  const int n = (idx >> 10) & (NN - 1);
  const int b = idx >> 14;

  const float aLC = ALC[d * NN + n];
  float h = 0.f;
  for (int c = 0; c < NC; ++c) {
    size_t off = ((size_t)(b * NC + c) * NN + n) * DD + d;
    float s = S[off];
    S[off] = h;
    h = aLC * h + s;
  }
  // block covers 256 consecutive d at one (b,n): reduce d, one atomic.
  __shared__ float red[256];
  red[threadIdx.x] = h;
  __syncthreads();
#pragma unroll
  for (int s2 = 128; s2 > 0; s2 >>= 1) {
    if (threadIdx.x < s2) red[threadIdx.x] += red[threadIdx.x + s2];
    __syncthreads();
  }
  if (threadIdx.x == 0) atomicAdd(&fs[b * NN + n], red[0] * (1.f / (float)DD));
}

// ---------------------------------------------------------------------------
// Scan phase 3: replay from H0, y*silu(gate) -> Y1b bf16. Same wave-private
// barrier-free structure as phase 1.
// ---------------------------------------------------------------------------
__global__ __launch_bounds__(256) void scan_final_k(
    const ushort_t* __restrict__ XCb, const ushort_t* __restrict__ XGb,
    const float* __restrict__ BC, const float* __restrict__ Adis,
    const float* __restrict__ D_param, const float* __restrict__ H0,
    ushort_t* __restrict__ Y1b) {
  const int b = blockIdx.x;
  const int w = threadIdx.x >> 6;
  const int lane = threadIdx.x & 63;
  const int c = blockIdx.y * 4 + w;
  const int d0 = blockIdx.z * 128 + lane * 2;
  const int t0 = c * LC;
  const size_t rowb = (size_t)b * LL;

  __shared__ float bcs_all[4][LC * 32];
  float* bcs = bcs_all[w];
  {
    const float4* src = (const float4*)(BC + (rowb + t0) * 32);
    float4* dst = (float4*)bcs;
#pragma unroll
    for (int i = 0; i < 4; ++i) dst[lane + i * 64] = src[lane + i * 64];
  }
  f32x4 av[8];
#pragma unroll
  for (int i = 0; i < 8; ++i) av[i] = *(const f32x4*)(Adis + d0 * 16 + i * 4);

  float h0[NN], h1[NN];
  const float* hp = H0 + ((size_t)(b * NC + c) * NN) * DD + d0;
#pragma unroll
  for (int n = 0; n < NN; ++n) {
    float2 v = *(const float2*)(hp + (size_t)n * DD);
    h0[n] = v.x;
    h1[n] = v.y;
  }
  float2 Dp = *(const float2*)(D_param + d0);

  const ushort_t* xp = XCb + (rowb + t0) * DD + d0;
  const ushort_t* gp = XGb + (rowb + t0) * 2048 + DD + d0;
  ushort_t* yp = Y1b + (rowb + t0) * DD + d0;
  u32 xw = *(const u32*)xp;
  u32 gw = *(const u32*)gp;
  for (int t = 0; t < LC; ++t) {
    u32 xw_n = 0u, gw_n = 0u;
    if (t + 1 < LC) {
      xw_n = *(const u32*)(xp + (size_t)(t + 1) * DD);
      gw_n = *(const u32*)(gp + (size_t)(t + 1) * 2048);
    }
    float x0 = bf2f((ushort_t)(xw & 0xffff));
    float x1 = bf2f((ushort_t)(xw >> 16));
    float g0 = bf2f((ushort_t)(gw & 0xffff));
    float g1 = bf2f((ushort_t)(gw >> 16));
    float y0 = Dp.x * x0, y1 = Dp.y * x1;
    const float* bp = bcs + t * 32;
#pragma unroll
    for (int n = 0; n < NN; ++n) {
      float bv = bp[n], cv = bp[16 + n];
      h0[n] = av[n >> 2][n & 3] * h0[n] + x0 * bv;
      h1[n] = av[4 + (n >> 2)][n & 3] * h1[n] + x1 * bv;
      y0 += cv * h0[n];
      y1 += cv * h1[n];
    }
    float sg0 = g0 / (1.f + __expf(-g0));
    float sg1 = g1 / (1.f + __expf(-g1));
    u32 outw = (u32)f2bf(y0 * sg0) | ((u32)f2bf(y1 * sg1) << 16);
    *(u32*)(yp + (size_t)t * DD) = outw;
    xw = xw_n;
    gw = gw_n;
  }
}

// ---------------------------------------------------------------------------
extern "C" void kernel_launch(void* const* d_in, const int* in_sizes, int n_in,
                              void* d_out, int out_size, void* d_ws,
                              size_t ws_size, hipStream_t stream) {
  const float* x = (const float*)d_in[0];
  const float* W_in = (const float*)d_in[1];
  const float* b_in = (const float*)d_in[2];
  const float* conv_w = (const float*)d_in[3];
  const float* conv_b = (const float*)d_in[4];
  const float* W_x = (const float*)d_in[5];
  const float* b_x = (const float*)d_in[6];
  const float* A_log = (const float*)d_in[7];
  const float* D_param = (const float*)d_in[8];
  const float* W_out = (const float*)d_in[9];
  const float* b_out = (const float*)d_in[10];
  float* out = (float*)d_out;
  float* fs = out + (size_t)MM * DD;

  // ws layout: f32 regions then bf16 regions (all 16B-aligned)
  float* BC = (float*)d_ws;                    // [8192*32] f32
  float* S = BC + (size_t)MM * 32;             // [2*128*16*1024] f32 (16.8MB)
  float* Adis = S + (size_t)BB * NC * NN * DD; // [1024*16] f32
  float* ALC = Adis + (size_t)DD * NN;         // [1024*16] f32
  ushort_t* Xb = (ushort_t*)(ALC + (size_t)DD * NN);  // [8192*1024] bf16
  ushort_t* XGb = Xb + (size_t)MM * DD;        // [8192*2048] bf16
  ushort_t* XCb = XGb + (size_t)MM * 2048;     // [8192*1024] bf16
  ushort_t* Y1b = XCb + (size_t)MM * DD;       // [8192*1024] bf16
  ushort_t* WinT = Y1b + (size_t)MM * DD;      // [2048*1024] bf16
  ushort_t* WoutT = WinT + (size_t)2048 * DD;  // [1024*1024] bf16
  ushort_t* WxT = WoutT + (size_t)DD * DD;     // [32*1024] bf16

  dim3 blk(256);
  // 1. prep: cast x, fs zero, weight transposes, decay tables
  prep_k<<<dim3(64, 128, 2), blk, 0, stream>>>(x, Xb, fs, W_in, W_out, W_x,
                                               WinT, WoutT, WxT, A_log, Adis,
                                               ALC);
  // 2. in-proj (bf16 MFMA, bf16 out): XGb = x @ W_in + b_in
  gemm_bt_mfma<true><<<dim3(2048 / 128, MM / 128), blk, 0, stream>>>(
      Xb, WinT, b_in, XGb, 2048);
  // 3. conv + silu -> XCb (bf16)
  conv_silu_k<<<dim3((MM * 128) / 256), blk, 0, stream>>>(XGb, conv_w, conv_b,
                                                          XCb);
  // 4. BC proj (bf16 MFMA): BC = x_conv @ W_x + b_x
  bc_mfma_k<<<dim3(MM / 32), dim3(128), 0, stream>>>(XCb, WxT, b_x, BC);
  // 5. scan phase 1 (barrier-free, 4 chunks/block)
  scan_local_k<<<dim3(BB, NC / 4, DD / 128), blk, 0, stream>>>(XCb, BC, Adis,
                                                               S);
  // 6. carry + final-state mean
  scan_carry_k<<<dim3((BB * DD * NN) / 256), blk, 0, stream>>>(S, ALC, fs);
  // 7. scan phase 3 -> Y1 bf16
  scan_final_k<<<dim3(BB, NC / 4, DD / 128), blk, 0, stream>>>(
      XCb, XGb, BC, Adis, D_param, S, Y1b);
  // 8. out-proj (bf16 MFMA, f32 out): out = Y1 @ W_out + b_out
  gemm_bt_mfma<false><<<dim3(1024 / 128, MM / 128), blk, 0, stream>>>(
      Y1b, WoutT, b_out, out, 1024);
}